// Round 2
// baseline (448.730 us; speedup 1.0000x reference)
//
#include <hip/hip_runtime.h>

#define NVOX (64 * 64 * 64)          // voxels per (b) volume = 262144
#define FM (2 * 8 * NVOX)            // floats per mask field = 4,194,304 (16.8 MB)

// Mask encoding: 0 = pred-fg, 1 = target-fg, 2 = pred-bg, 3 = target-bg.
// stack(m) = m & 1 (0 -> pred, 1 -> target); bg masks are m >= 2.

// ---------------------------------------------------------------------------
// Kernel 1: per-voxel softmax stats (dice S1/S2/N per (b,c) + CE) and has_fg
// flags. One thread per voxel column (b, x, y, z); C = 8 in registers.
// ---------------------------------------------------------------------------
__global__ __launch_bounds__(256) void k_stats(const float* __restrict__ in,
                                               const int* __restrict__ tg,
                                               float* __restrict__ accF,
                                               int* __restrict__ flags) {
    int v = blockIdx.x * 256 + threadIdx.x;   // 0 .. 524287
    int b = v >> 18;
    int r = v & (NVOX - 1);
    int t = tg[v];

    float xs[8];
#pragma unroll
    for (int c = 0; c < 8; ++c) xs[c] = in[(b * 8 + c) * NVOX + r];

    float mx = xs[0];
#pragma unroll
    for (int c = 1; c < 8; ++c) mx = fmaxf(mx, xs[c]);
    float ex[8];
    float se = 0.f;
#pragma unroll
    for (int c = 0; c < 8; ++c) { ex[c] = expf(xs[c] - mx); se += ex[c]; }
    float inv = 1.0f / se;
    float lse = mx + logf(se);

    // logit at target channel without runtime register indexing
    float xt = xs[0];
#pragma unroll
    for (int c = 1; c < 8; ++c) xt = (t == c) ? xs[c] : xt;

    float red[25];
#pragma unroll
    for (int c = 0; c < 8; ++c) {
        float p = ex[c] * inv;
        red[c] = p;                               // S1 = sum probs
        red[8 + c] = (t == c) ? p : 0.f;          // S2 = sum probs*onehot
        red[16 + c] = (t == c) ? 1.f : 0.f;       // N  = class voxel count
    }
    red[24] = lse - xt;                           // -log p_target

#pragma unroll
    for (int k = 0; k < 25; ++k) {
        float s = red[k];
        s += __shfl_down(s, 32);
        s += __shfl_down(s, 16);
        s += __shfl_down(s, 8);
        s += __shfl_down(s, 4);
        s += __shfl_down(s, 2);
        s += __shfl_down(s, 1);
        red[k] = s;
    }

    int lane = threadIdx.x & 63;
    int wid = threadIdx.x >> 6;
    __shared__ float part[4][25];
    if (lane == 0) {
#pragma unroll
        for (int k = 0; k < 25; ++k) part[wid][k] = red[k];
    }

    // has_fg (pred: any logit > 0.5 anywhere in (C,X,Y,Z); target: always)
    bool anyP = false;
#pragma unroll
    for (int c = 0; c < 8; ++c) anyP = anyP || (xs[c] > 0.5f);
    if (__any(anyP) && lane == 0) atomicOr(&flags[b], 1);
    if (threadIdx.x == 0) atomicOr(&flags[2 + b], 1);

    __syncthreads();
    if (threadIdx.x < 25) {
        float s = part[0][threadIdx.x] + part[1][threadIdx.x] +
                  part[2][threadIdx.x] + part[3][threadIdx.x];
        atomicAdd(&accF[b * 25 + threadIdx.x], s);
    }
}

// ---------------------------------------------------------------------------
// Kernel 2: build masks [M0, M0+NM) and run the exact C-axis (n=8) min-plus
// DT in registers; write f[NM][B][C][X][Y][Z] (squared distances).
// ---------------------------------------------------------------------------
template <int M0, int NM>
__global__ __launch_bounds__(256) void k_mask(const float* __restrict__ in,
                                              const int* __restrict__ tg,
                                              float* __restrict__ f) {
    int v = blockIdx.x * 256 + threadIdx.x;
    int b = v >> 18;
    int r = v & (NVOX - 1);
    int t = tg[v];

    float xs[8];
#pragma unroll
    for (int c = 0; c < 8; ++c) xs[c] = in[(b * 8 + c) * NVOX + r];

#pragma unroll
    for (int mi = 0; mi < NM; ++mi) {
        constexpr int MBASE = M0;
        int m = MBASE + mi;
        float fm[8];
#pragma unroll
        for (int c = 0; c < 8; ++c) {
            bool fg = ((m & 1) == 0) ? (xs[c] > 0.5f) : (t == c);
            bool hot = (m < 2) ? fg : !fg;        // bg masks are complements
            fm[c] = hot ? 1e9f : 0.f;
        }
#pragma unroll
        for (int i = 0; i < 8; ++i) {
            float d = 1e9f;
#pragma unroll
            for (int j = 0; j < 8; ++j) {
                float sq = (float)((i - j) * (i - j));
                d = fminf(d, fm[j] + sq);
            }
            f[(size_t)mi * FM + (b * 8 + i) * NVOX + r] = d;
        }
    }
}

// ---------------------------------------------------------------------------
// Kernels 3/4: exact 1-D DT along X (stride 4096) or Y (stride 64).
// One thread per line, line in registers. w[j] = f[j] + j^2;
// d[i] = min_j fma(-2i, j, w[j]) + i^2 -- exact integers in fp32.
// Grid supplies nm*16*4096 lines / 256.
// ---------------------------------------------------------------------------
template <int AXIS>
__global__ __launch_bounds__(256) void dt_pass(float* __restrict__ f) {
    int l = blockIdx.x * 256 + threadIdx.x;
    int base, stride;
    if constexpr (AXIS == 0) {                 // X: fixed (plane, y, z)
        base = (l >> 12) * NVOX + (l & 4095);
        stride = 4096;
    } else {                                   // Y: fixed (plane, x, z)
        base = (l >> 12) * NVOX + (((l >> 6) & 63) << 12) + (l & 63);
        stride = 64;
    }
    float* p = f + base;
    float w[64];
#pragma unroll
    for (int j = 0; j < 64; ++j) w[j] = p[j * stride] + (float)(j * j);
#pragma unroll 2
    for (int i = 0; i < 64; ++i) {
        float a = -2.0f * (float)i;
        float d = 3.0e38f;
#pragma unroll
        for (int j = 0; j < 64; ++j) d = fminf(d, fmaf(a, (float)j, w[j]));
        d += (float)(i * i);
        p[i * stride] = fminf(d, 1e9f);
    }
}

// ---------------------------------------------------------------------------
// Kernel 5: DT along contiguous Z via padded LDS tile (conflict-free).
// Grid supplies nm * 512 blocks of 128 lines.
// ---------------------------------------------------------------------------
__global__ __launch_bounds__(128) void dt_pass_z(float* __restrict__ f) {
    __shared__ float tile[128 * 65];
    size_t base = (size_t)blockIdx.x * 8192;   // 128 lines * 64 elems
    int tid = threadIdx.x;
#pragma unroll
    for (int k = 0; k < 64; ++k) {
        int idx = k * 128 + tid;
        tile[(idx >> 6) * 65 + (idx & 63)] = f[base + idx];
    }
    __syncthreads();
    float w[64];
    float* row = &tile[tid * 65];
#pragma unroll
    for (int j = 0; j < 64; ++j) w[j] = row[j] + (float)(j * j);
#pragma unroll 2
    for (int i = 0; i < 64; ++i) {
        float a = -2.0f * (float)i;
        float d = 3.0e38f;
#pragma unroll
        for (int j = 0; j < 64; ++j) d = fminf(d, fmaf(a, (float)j, w[j]));
        d += (float)(i * i);
        row[i] = fminf(d, 1e9f);
    }
    __syncthreads();
#pragma unroll
    for (int k = 0; k < 64; ++k) {
        int idx = k * 128 + tid;
        f[base + idx] = tile[(idx >> 6) * 65 + (idx & 63)];
    }
}

// ---------------------------------------------------------------------------
// Kernel 6: accumulate sum( e^2 * sum_m flag_m * f_m ) for chunk [M0, M0+NM).
// No sqrt: field^2 = f_fg + f_bg exactly (cross term vanishes pointwise).
// ---------------------------------------------------------------------------
template <int M0, int NM>
__global__ __launch_bounds__(256) void k_hd_acc(const float* __restrict__ in,
                                                const int* __restrict__ tg,
                                                const float* __restrict__ f,
                                                const int* __restrict__ flags,
                                                double* __restrict__ hd) {
    int v = blockIdx.x * 256 + threadIdx.x;
    int b = v >> 18;
    int r = v & (NVOX - 1);
    int t = tg[v];
    float fl[NM];
#pragma unroll
    for (int mi = 0; mi < NM; ++mi) {
        int m = M0 + mi;
        fl[mi] = flags[((m & 1) ? 2 : 0) + b] ? 1.f : 0.f;
    }
    float local = 0.f;
#pragma unroll
    for (int c = 0; c < 8; ++c) {
        int ci = (b * 8 + c) * NVOX + r;
        float x = in[ci];
        float oh = (t == c) ? 1.f : 0.f;
        float e = x - oh;
        float dsum = 0.f;
#pragma unroll
        for (int mi = 0; mi < NM; ++mi)
            dsum += fl[mi] * f[(size_t)mi * FM + ci];
        local += (e * e) * dsum;
    }
    float s = local;
    s += __shfl_down(s, 32);
    s += __shfl_down(s, 16);
    s += __shfl_down(s, 8);
    s += __shfl_down(s, 4);
    s += __shfl_down(s, 2);
    s += __shfl_down(s, 1);
    __shared__ float part[4];
    int lane = threadIdx.x & 63;
    int wid = threadIdx.x >> 6;
    if (lane == 0) part[wid] = s;
    __syncthreads();
    if (threadIdx.x == 0) {
        float bs = part[0] + part[1] + part[2] + part[3];
        atomicAdd(hd, (double)bs);
    }
}

// ---------------------------------------------------------------------------
// Kernel 7: assemble scalar loss
// ---------------------------------------------------------------------------
__global__ void k_final(const float* __restrict__ accF,
                        const double* __restrict__ hd,
                        float* __restrict__ out) {
    float dsum = 0.f;
    for (int c = 1; c < 8; ++c) {
        float sc = 0.f;
        for (int b = 0; b < 2; ++b) {
            float S1 = accF[b * 25 + c];
            float S2 = accF[b * 25 + 8 + c];
            float Nc = accF[b * 25 + 16 + c];
            float tps = S2;
            float fps = (S1 - S2);              // * ALPHA_T (=1)
            float fns = (Nc - S2);              // * BETA_T  (=1)
            sc += 2.f * tps / (2.f * tps + fps + fns + 1e-5f);
        }
        dsum += sc * 0.5f;                      // mean over batch
    }
    float dice = 1.f - dsum / 7.f;              // mean over channels 1..7
    float ce = (accF[24] + accF[25 + 24]) / 524288.f;
    float hdv = (float)(hd[0] / 4194304.0);
    out[0] = dice + ce + hdv;
}

// ---------------------------------------------------------------------------
template <int M0, int NM>
static void run_chunk(const float* in, const int* tg, float* f,
                      const int* flags, double* hd, hipStream_t stream) {
    k_mask<M0, NM><<<2048, 256, 0, stream>>>(in, tg, f);
    dt_pass<0><<<NM * 256, 256, 0, stream>>>(f);   // X axis
    dt_pass<1><<<NM * 256, 256, 0, stream>>>(f);   // Y axis
    dt_pass_z<<<NM * 512, 128, 0, stream>>>(f);    // Z axis
    k_hd_acc<M0, NM><<<2048, 256, 0, stream>>>(in, tg, f, flags, hd);
}

extern "C" void kernel_launch(void* const* d_in, const int* in_sizes, int n_in,
                              void* d_out, int out_size, void* d_ws, size_t ws_size,
                              hipStream_t stream) {
    const float* in = (const float*)d_in[0];
    const int* tg = (const int*)d_in[1];
    float* out = (float*)d_out;

    // acc block (256 B) at the END of the workspace, 256-aligned.
    size_t acc_off = ((ws_size - 256) / 256) * 256;
    char* accB = (char*)d_ws + acc_off;
    double* hd = (double*)accB;                    // @0   : double
    float* accF = (float*)(accB + 8);              // @8   : float[2][25]
    int* flags = (int*)(accB + 208);               // @208 : int[4]
    float* f = (float*)d_ws;

    // how many 16.8 MB mask fields fit before the acc block?
    int nm_cap = (int)(acc_off / ((size_t)FM * 4));

    hipMemsetAsync(accB, 0, 256, stream);
    k_stats<<<2048, 256, 0, stream>>>(in, tg, accF, flags);

    if (nm_cap >= 4) {
        run_chunk<0, 4>(in, tg, f, flags, hd, stream);
    } else if (nm_cap >= 2) {
        run_chunk<0, 2>(in, tg, f, flags, hd, stream);
        run_chunk<2, 2>(in, tg, f, flags, hd, stream);
    } else if (nm_cap >= 1) {
        run_chunk<0, 1>(in, tg, f, flags, hd, stream);
        run_chunk<1, 1>(in, tg, f, flags, hd, stream);
        run_chunk<2, 1>(in, tg, f, flags, hd, stream);
        run_chunk<3, 1>(in, tg, f, flags, hd, stream);
    }
    // if nm_cap == 0 the workspace is unusably small; produce stats-only
    // output (clean absmax failure instead of an OOB crash).

    k_final<<<1, 1, 0, stream>>>(accF, hd, out);
}

// Round 4
// 361.055 us; speedup vs baseline: 1.2428x; 1.2428x over previous
//
#include <hip/hip_runtime.h>

#define NVOX (64 * 64 * 64)          // 262144
#define FM (16 * NVOX)               // floats per mask field (B*C*XYZ) = 4,194,304

// Mask encoding: 0 = pred-fg, 1 = target-fg, 2 = pred-bg, 3 = target-bg.
// Axis order: Z (binary O(n) scan) -> Y (windowed min-plus) -> X (windowed)
// -> C (n=8, fused into HD reduction). 1-D exact min-plus passes commute and
// all finite values are exact small integers in fp32 => bitwise-identical to
// the reference's O(n^2) scan (verified absmax 0.0 in round 2).

// ---------------------------------------------------------------------------
// Kernel 1: dice stats + CE + pred has_fg. 65536 threads, 8 voxel-columns
// each, register accumulators; LDS cross-wave reduce; 25 atomics per block.
// ---------------------------------------------------------------------------
__global__ __launch_bounds__(256, 4) void k_stats(const float* __restrict__ in,
                                                  const int* __restrict__ tg,
                                                  float* __restrict__ accF,
                                                  int* __restrict__ flags) {
    int tid0 = blockIdx.x * 256 + threadIdx.x;   // 0 .. 65535
    int lane = threadIdx.x & 63;
    int wid = threadIdx.x >> 6;
    __shared__ float part[4][25];
    __shared__ int af;

    for (int b = 0; b < 2; ++b) {
        float S1[8], S2[8], NN[8];
        float ce = 0.f;
        bool anyP = false;
#pragma unroll
        for (int c = 0; c < 8; ++c) { S1[c] = 0.f; S2[c] = 0.f; NN[c] = 0.f; }
        for (int ch = 0; ch < 4; ++ch) {
            int r = ch * 65536 + tid0;           // voxel within volume b
            int t = tg[b * NVOX + r];
            float xs[8];
#pragma unroll
            for (int c = 0; c < 8; ++c) xs[c] = in[(b * 8 + c) * NVOX + r];
            float mx = xs[0];
#pragma unroll
            for (int c = 1; c < 8; ++c) mx = fmaxf(mx, xs[c]);
            float ex[8];
            float se = 0.f;
#pragma unroll
            for (int c = 0; c < 8; ++c) { ex[c] = expf(xs[c] - mx); se += ex[c]; }
            float inv = 1.f / se;
            float lse = mx + logf(se);
            float xt = xs[0];
#pragma unroll
            for (int c = 1; c < 8; ++c) xt = (t == c) ? xs[c] : xt;
            ce += lse - xt;
#pragma unroll
            for (int c = 0; c < 8; ++c) {
                float p = ex[c] * inv;
                S1[c] += p;
                S2[c] += (t == c) ? p : 0.f;
                NN[c] += (t == c) ? 1.f : 0.f;
                anyP = anyP || (xs[c] > 0.5f);
            }
        }
        float red[25];
#pragma unroll
        for (int c = 0; c < 8; ++c) {
            red[c] = S1[c]; red[8 + c] = S2[c]; red[16 + c] = NN[c];
        }
        red[24] = ce;
#pragma unroll
        for (int k = 0; k < 25; ++k) {
            float s = red[k];
            s += __shfl_down(s, 32);
            s += __shfl_down(s, 16);
            s += __shfl_down(s, 8);
            s += __shfl_down(s, 4);
            s += __shfl_down(s, 2);
            s += __shfl_down(s, 1);
            red[k] = s;
        }
        if (threadIdx.x == 0) af = 0;
        __syncthreads();                 // also covers af init
        if (lane == 0) {
#pragma unroll
            for (int k = 0; k < 25; ++k) part[wid][k] = red[k];
            if (__any(anyP)) atomicOr(&af, 1);
        } else {
            (void)__any(anyP);           // keep ballot wave-uniform
        }
        __syncthreads();
        if (threadIdx.x < 25) {
            float s = part[0][threadIdx.x] + part[1][threadIdx.x] +
                      part[2][threadIdx.x] + part[3][threadIdx.x];
            atomicAdd(&accF[b * 25 + threadIdx.x], s);
        }
        if (threadIdx.x == 0 && af) atomicOr(&flags[b], 1);
        __syncthreads();                 // protect part[] reuse for b=1
    }
}

// ---------------------------------------------------------------------------
// Kernel 2 (fused mask + Z + Y): one block (64 thr) per (mask, b, c, x) slab.
// Build binary mask of the (y,z) slab in LDS, O(n) binary Z scan, exact
// windowed min-plus along Y, write squared distances to f.
// ---------------------------------------------------------------------------
template <int M0>
__global__ __launch_bounds__(64) void k_mask_zy(const float* __restrict__ in,
                                                const int* __restrict__ tg,
                                                float* __restrict__ f) {
    __shared__ float tile[64 * 65];
    int blk = blockIdx.x;
    int m = M0 + (blk >> 10);
    int s = blk & 1023;
    int b = s >> 9, c = (s >> 6) & 7, x = s & 63;
    int tid = threadIdx.x;

    if ((m & 1) == 0) {            // pred masks from logits channel c
        const float* src = in + (b * 8 + c) * NVOX + x * 4096;
#pragma unroll 8
        for (int k = 0; k < 64; ++k) {
            bool fg = src[k * 64 + tid] > 0.5f;
            bool hot = (m < 2) ? fg : !fg;
            tile[k * 65 + tid] = hot ? 1e9f : 0.f;
        }
    } else {                       // target masks from labels
        const int* src = tg + b * NVOX + x * 4096;
#pragma unroll 8
        for (int k = 0; k < 64; ++k) {
            bool fg = (src[k * 64 + tid] == c);
            bool hot = (m < 2) ? fg : !fg;
            tile[k * 65 + tid] = hot ? 1e9f : 0.f;
        }
    }
    __syncthreads();

    // Z pass (binary): nearest-seed run-length scan, O(n). Row y = tid.
    {
        float* row = &tile[tid * 65];
        float g = 1000.f;
#pragma unroll 8
        for (int z = 0; z < 64; ++z) {
            float v = row[z];
            g = (v == 0.f) ? 0.f : g + 1.f;
            row[z] = g;            // forward distance (seed iff 0)
        }
        g = 1000.f;
#pragma unroll 8
        for (int z = 63; z >= 0; --z) {
            float gf = row[z];
            g = (gf == 0.f) ? 0.f : g + 1.f;
            float d = fminf(gf, g);
            row[z] = (d > 63.f) ? 1e9f : d * d;   // exact int^2 or 1e9
        }
    }
    __syncthreads();

    // Y pass: exact windowed min-plus, column z = tid. Window |i-j| <= Ri,
    // Ri = floor(sqrt(d0)) + 1 > sqrt(d0) => excluded j cannot improve.
    float* out = f + (size_t)(blk >> 10) * FM + (b * 8 + c) * NVOX + x * 4096;
    for (int i = 0; i < 64; ++i) {
        float d0 = tile[i * 65 + tid];
        float d = d0;
        int Ri = (int)sqrtf(d0) + 1;
        Ri = (Ri > 63) ? 63 : Ri;
        for (int dd = 1; dd <= Ri; ++dd) {
            float q = (float)(dd * dd);
            int jl = i - dd, jr = i + dd;
            float cl = (jl >= 0) ? tile[jl * 65 + tid] : 1e9f;
            float cr = (jr < 64) ? tile[jr * 65 + tid] : 1e9f;
            d = fminf(d, fminf(cl, cr) + q);
        }
        out[i * 64 + tid] = fminf(d, 1e9f);
    }
}

// ---------------------------------------------------------------------------
// Kernel 3: X pass, windowed min-plus. 128 lines/block; each thread's line
// in its own private LDS row (stride 65 -> conflict-free, no barriers).
// ---------------------------------------------------------------------------
template <int M0>
__global__ __launch_bounds__(128, 4) void k_dtx(float* __restrict__ f) {
    __shared__ float wl[128 * 65];    // 33 KB
    int blk = blockIdx.x;
    int mi = blk >> 9;
    int s = blk & 511;
    int plane = s >> 5;               // b*8 + c
    int y0 = (s & 31) * 2;
    int tid = threadIdx.x;
    float* fb = f + (size_t)mi * FM + plane * NVOX + y0 * 64;

#pragma unroll 8
    for (int j = 0; j < 64; ++j) wl[tid * 65 + j] = fb[j * 4096 + tid];

    float* row = &wl[tid * 65];
    for (int i = 0; i < 64; ++i) {
        float d0 = row[i];
        float d = d0;
        int Ri = (int)sqrtf(d0) + 1;
        Ri = (Ri > 63) ? 63 : Ri;
        for (int dd = 1; dd <= Ri; ++dd) {
            float q = (float)(dd * dd);
            int jl = i - dd, jr = i + dd;
            float cl = (jl >= 0) ? row[jl] : 1e9f;
            float cr = (jr < 64) ? row[jr] : 1e9f;
            d = fminf(d, fminf(cl, cr) + q);
        }
        fb[i * 4096 + tid] = fminf(d, 1e9f);
    }
}

// ---------------------------------------------------------------------------
// Kernel 4: C-axis (n=8) min-plus in registers + fused HD reduction.
// field^2 = f_fg + f_bg pointwise (cross term vanishes) => no sqrt.
// ---------------------------------------------------------------------------
template <int M0, int NM>
__global__ __launch_bounds__(256, 4) void k_cdt_hd(const float* __restrict__ in,
                                                   const int* __restrict__ tg,
                                                   const float* __restrict__ f,
                                                   const int* __restrict__ flags,
                                                   double* __restrict__ hd) {
    int v = blockIdx.x * 256 + threadIdx.x;
    int b = v >> 18;
    int r = v & (NVOX - 1);
    int t = tg[v];

    float e2[8];
#pragma unroll
    for (int c = 0; c < 8; ++c) {
        float e = in[(b * 8 + c) * NVOX + r] - ((t == c) ? 1.f : 0.f);
        e2[c] = e * e;
    }
    float acc = 0.f;
#pragma unroll
    for (int mi = 0; mi < NM; ++mi) {
        int m = M0 + mi;
        float fl = (m & 1) ? 1.f : (flags[b] ? 1.f : 0.f);  // target always has fg
        float fm[8];
#pragma unroll
        for (int c = 0; c < 8; ++c)
            fm[c] = f[(size_t)mi * FM + (b * 8 + c) * NVOX + r];
        float am = 0.f;
#pragma unroll
        for (int i = 0; i < 8; ++i) {
            float d = 1e9f;
#pragma unroll
            for (int j = 0; j < 8; ++j)
                d = fminf(d, fm[j] + (float)((i - j) * (i - j)));
            am += e2[i] * d;
        }
        acc += fl * am;
    }
    float ssum = acc;
    ssum += __shfl_down(ssum, 32);
    ssum += __shfl_down(ssum, 16);
    ssum += __shfl_down(ssum, 8);
    ssum += __shfl_down(ssum, 4);
    ssum += __shfl_down(ssum, 2);
    ssum += __shfl_down(ssum, 1);
    __shared__ float part[4];
    int lane = threadIdx.x & 63;
    int wid = threadIdx.x >> 6;
    if (lane == 0) part[wid] = ssum;
    __syncthreads();
    if (threadIdx.x == 0)
        atomicAdd(hd, (double)(part[0] + part[1] + part[2] + part[3]));
}

// ---------------------------------------------------------------------------
// Kernel 5: assemble scalar loss
// ---------------------------------------------------------------------------
__global__ void k_final(const float* __restrict__ accF,
                        const double* __restrict__ hd,
                        float* __restrict__ out) {
    float dsum = 0.f;
    for (int c = 1; c < 8; ++c) {
        float sc = 0.f;
        for (int b = 0; b < 2; ++b) {
            float S1 = accF[b * 25 + c];
            float S2 = accF[b * 25 + 8 + c];
            float Nc = accF[b * 25 + 16 + c];
            sc += 2.f * S2 / (2.f * S2 + (S1 - S2) + (Nc - S2) + 1e-5f);
        }
        dsum += sc * 0.5f;
    }
    float dice = 1.f - dsum / 7.f;
    float ce = (accF[24] + accF[25 + 24]) / 524288.f;
    float hdv = (float)(hd[0] / 4194304.0);
    out[0] = dice + ce + hdv;
}

// ---------------------------------------------------------------------------
template <int M0, int NM>
static void run_chunk(const float* in, const int* tg, float* f,
                      const int* flags, double* hd, hipStream_t stream) {
    k_mask_zy<M0><<<NM * 1024, 64, 0, stream>>>(in, tg, f);
    k_dtx<M0><<<NM * 512, 128, 0, stream>>>(f);
    k_cdt_hd<M0, NM><<<2048, 256, 0, stream>>>(in, tg, f, flags, hd);
}

extern "C" void kernel_launch(void* const* d_in, const int* in_sizes, int n_in,
                              void* d_out, int out_size, void* d_ws, size_t ws_size,
                              hipStream_t stream) {
    const float* in = (const float*)d_in[0];
    const int* tg = (const int*)d_in[1];
    float* out = (float*)d_out;

    size_t acc_off = ((ws_size - 256) / 256) * 256;
    char* accB = (char*)d_ws + acc_off;
    double* hd = (double*)accB;                    // @0
    float* accF = (float*)(accB + 8);              // @8  : float[2][25]
    int* flags = (int*)(accB + 208);               // @208: int[2]
    float* f = (float*)d_ws;

    int nm_cap = (int)(acc_off / ((size_t)FM * 4));

    hipMemsetAsync(accB, 0, 256, stream);
    k_stats<<<256, 256, 0, stream>>>(in, tg, accF, flags);

    if (nm_cap >= 4) {
        run_chunk<0, 4>(in, tg, f, flags, hd, stream);
    } else if (nm_cap >= 2) {
        run_chunk<0, 2>(in, tg, f, flags, hd, stream);
        run_chunk<2, 2>(in, tg, f, flags, hd, stream);
    } else if (nm_cap >= 1) {
        run_chunk<0, 1>(in, tg, f, flags, hd, stream);
        run_chunk<1, 1>(in, tg, f, flags, hd, stream);
        run_chunk<2, 1>(in, tg, f, flags, hd, stream);
        run_chunk<3, 1>(in, tg, f, flags, hd, stream);
    }

    k_final<<<1, 1, 0, stream>>>(accF, hd, out);
}